// Round 5
// baseline (672.129 us; speedup 1.0000x reference)
//
#include <hip/hip_runtime.h>
#include <math.h>

#define DIM 256
#define NSLOTS 8
#define TOKENS 4096
#define BATCH 64

typedef __attribute__((ext_vector_type(8))) short bf16x8;
typedef __attribute__((ext_vector_type(4))) float f32x4;

union U4B { uint4 u; bf16x8 b; };

// ---------- helpers ----------
__device__ __forceinline__ float wsum(float v) {
#pragma unroll
  for (int m = 32; m >= 1; m >>= 1) v += __shfl_xor(v, m);
  return v;
}
__device__ __forceinline__ float wmax(float v) {
#pragma unroll
  for (int m = 32; m >= 1; m >>= 1) v = fmaxf(v, __shfl_xor(v, m));
  return v;
}
__device__ __forceinline__ unsigned short f2bf(float f) {
  unsigned u = __float_as_uint(f);
  u += 0x7fffu + ((u >> 16) & 1u);
  return (unsigned short)(u >> 16);
}
__device__ __forceinline__ float sigmf(float x) { return 1.f / (1.f + expf(-x)); }

// ---------- K0: 32x32 tiled fp32 transpose src[R][C] -> dst[C][R] ----------
__global__ __launch_bounds__(256) void k_tr(const float* __restrict__ src,
                                            float* __restrict__ dst, int R, int C) {
  __shared__ float t[32][33];
  int c0 = blockIdx.x * 32, r0 = blockIdx.y * 32;
  int ci = threadIdx.x & 31, r8 = threadIdx.x >> 5;
#pragma unroll
  for (int k = 0; k < 4; ++k) {
    int r = r8 + k * 8;
    t[r][ci] = src[(size_t)(r0 + r) * C + c0 + ci];
  }
  __syncthreads();
#pragma unroll
  for (int k = 0; k < 4; ++k) {
    int r = r8 + k * 8;
    dst[(size_t)(c0 + r) * R + r0 + ci] = t[ci][r];
  }
}

// ---------- K1: LN(inputs) -> x bf16 row-major (packed pairs), coalesced ----------
__global__ __launch_bounds__(256) void k_ln_in(const float* __restrict__ in,
                                               const float* __restrict__ g,
                                               const float* __restrict__ b,
                                               unsigned* __restrict__ x) {
  int row = blockIdx.x * 4 + (threadIdx.x >> 6);
  int lane = threadIdx.x & 63;
  const float* p = in + (size_t)row * DIM + lane * 4;
  float4 v = *(const float4*)p;
  float s  = wsum(v.x + v.y + v.z + v.w);
  float sq = wsum(v.x * v.x + v.y * v.y + v.z * v.z + v.w * v.w);
  float mu = s * (1.f / 256.f);
  float var = sq * (1.f / 256.f) - mu * mu;
  float rs = rsqrtf(var + 1e-5f);
  float4 gg = *(const float4*)(g + lane * 4);
  float4 bb = *(const float4*)(b + lane * 4);
  float y0 = (v.x - mu) * rs * gg.x + bb.x;
  float y1 = (v.y - mu) * rs * gg.y + bb.y;
  float y2 = (v.z - mu) * rs * gg.z + bb.z;
  float y3 = (v.w - mu) * rs * gg.w + bb.w;
  uint2 o;
  o.x = (unsigned)f2bf(y0) | ((unsigned)f2bf(y1) << 16);
  o.y = (unsigned)f2bf(y2) | ((unsigned)f2bf(y3) << 16);
  *(uint2*)(x + (size_t)row * 128 + lane * 2) = o;
}

// ---------- K1b: bf16 transpose x[n][t][d] -> xT[n][d][t], 128x128 tiles ----------
// grid (32 t-tiles, 2 d-tiles, 64 n), 256 threads. All global I/O coalesced.
__global__ __launch_bounds__(256) void k_trx(const unsigned* __restrict__ x,
                                             unsigned* __restrict__ xT) {
  __shared__ unsigned u[128][65];  // [t_local][d-pair], pad 65 -> benign conflicts
  int tt = blockIdx.x, dt = blockIdx.y, n = blockIdx.z;
  int tid = threadIdx.x;
  int t0 = tt * 128, c0 = dt * 64;  // c = d-pair index
  {
    int row = tid >> 1, half = tid & 1;
    const unsigned* sp = x + ((size_t)n * 4096 + t0 + row) * 128 + c0 + half * 32;
    unsigned* dr = &u[row][half * 32];
#pragma unroll
    for (int j = 0; j < 8; ++j) {
      uint4 vv = *(const uint4*)(sp + j * 4);
      dr[j * 4 + 0] = vv.x;
      dr[j * 4 + 1] = vv.y;
      dr[j * 4 + 2] = vv.z;
      dr[j * 4 + 3] = vv.w;
    }
  }
  __syncthreads();
#pragma unroll
  for (int p = 0; p < 8; ++p) {
    int dl = p * 16 + (tid >> 4);   // d_local 0..127
    int c = dl >> 1, hi = dl & 1;
    unsigned o[4];
#pragma unroll
    for (int k = 0; k < 4; ++k) {
      int j = (tid & 15) * 4 + k;   // t-pair index 0..63
      unsigned u0 = u[2 * j][c], u1 = u[2 * j + 1][c];
      unsigned h0 = hi ? (u0 >> 16) : (u0 & 0xffffu);
      unsigned h1 = hi ? (u1 >> 16) : (u1 & 0xffffu);
      o[k] = h0 | (h1 << 16);
    }
    unsigned* dp = xT + ((size_t)n * 256 + dt * 128 + dl) * 2048 + tt * 64 + (tid & 15) * 4;
    *(uint4*)dp = *(uint4*)&o[0];
  }
}

// ---------- K2: slots = mu + exp(logsigma)*noise ----------
__global__ __launch_bounds__(256) void k_init(const float* __restrict__ mu,
                                              const float* __restrict__ ls,
                                              const float* __restrict__ noise,
                                              float* __restrict__ slots) {
  int i = blockIdx.x * 256 + threadIdx.x;
  int sd = i & 2047;
  slots[i] = mu[sd] + expf(ls[sd]) * noise[i];
}

// ---------- K3: qw = LN(slots)@WqT@Wk * scale ; grid (64, 2), 4 slots/block ----------
__global__ __launch_bounds__(512) void k_qw2(const float* __restrict__ slots,
                                             const float* __restrict__ g,
                                             const float* __restrict__ b,
                                             const float* __restrict__ WqT,
                                             const float* __restrict__ Wk,
                                             float* __restrict__ qw) {
  __shared__ float ln[4][256];
  __shared__ float q[4][256];
  __shared__ float red[16];
  int n = blockIdx.x, sg = blockIdx.y * 4;
  int tid = threadIdx.x;
  {
    int sl = tid >> 7, qq = tid & 127;
    const float* sp = slots + ((size_t)n * 8 + sg + sl) * 256;
    float v0 = sp[qq], v1 = sp[qq + 128];
    float ps = wsum(v0 + v1);
    float pq = wsum(v0 * v0 + v1 * v1);
    int wid = tid >> 6;
    if ((tid & 63) == 0) { red[wid] = ps; red[8 + wid] = pq; }
    __syncthreads();
    float ssum = red[sl * 2] + red[sl * 2 + 1];
    float sqq  = red[8 + sl * 2] + red[8 + sl * 2 + 1];
    float mu = ssum * (1.f / 256.f);
    float var = sqq * (1.f / 256.f) - mu * mu;
    float rs = rsqrtf(var + 1e-5f);
    ln[sl][qq]       = (v0 - mu) * rs * g[qq] + b[qq];
    ln[sl][qq + 128] = (v1 - mu) * rs * g[qq + 128] + b[qq + 128];
  }
  __syncthreads();
  int e = tid & 255, h = tid >> 8;
  {
    float a0 = 0.f, a1 = 0.f;
    for (int d = 0; d < 256; ++d) {
      float w = WqT[d * 256 + e];
      a0 += ln[h * 2][d] * w;
      a1 += ln[h * 2 + 1][d] * w;
    }
    q[h * 2][e] = a0;
    q[h * 2 + 1][e] = a1;
  }
  __syncthreads();
  {
    float a0 = 0.f, a1 = 0.f;
    for (int ee = 0; ee < 256; ++ee) {
      float w = Wk[(size_t)ee * 256 + e];
      a0 += q[h * 2][ee] * w;
      a1 += q[h * 2 + 1][ee] * w;
    }
    qw[((size_t)n * 8 + sg + h * 2) * 256 + e]     = a0 * 0.0625f;
    qw[((size_t)n * 8 + sg + h * 2 + 1) * 256 + e] = a1 * 0.0625f;
  }
}

// ---------- K4: logits via MFMA: logits[s][t] = sum_d qw[s][d] x[t][d] ----------
__global__ __launch_bounds__(256) void k_logits_m(const unsigned* __restrict__ x,
                                                  const float* __restrict__ qw,
                                                  float* __restrict__ logits) {
  int n = blockIdx.y;
  int tid = threadIdx.x, wv = tid >> 6, l = tid & 63;
  int col = l & 15, g = l >> 4;
  bf16x8 a[8];
  {
    const float* qp = qw + ((size_t)n * 8 + (col & 7)) * 256 + g * 8;
#pragma unroll
    for (int kk = 0; kk < 8; ++kk) {
      bf16x8 t;
#pragma unroll
      for (int i = 0; i < 8; ++i) t[i] = (short)f2bf(qp[kk * 32 + i]);
      a[kk] = t;
    }
  }
  int tbase = blockIdx.x * 256 + wv * 64;
#pragma unroll
  for (int tt = 0; tt < 4; ++tt) {
    int t0 = tbase + tt * 16;
    const unsigned* bp = x + ((size_t)n * 4096 + t0 + col) * 128 + g * 4;
    f32x4 acc = {0.f, 0.f, 0.f, 0.f};
#pragma unroll
    for (int kk = 0; kk < 8; ++kk) {
      U4B bb;
      bb.u = *(const uint4*)(bp + kk * 16);
      acc = __builtin_amdgcn_mfma_f32_16x16x32_bf16(a[kk], bb.b, acc, 0, 0, 0);
    }
    if (g < 2) {
      float* lp = logits + (((size_t)n * 8) + g * 4) * 4096 + t0 + col;
#pragma unroll
      for (int r = 0; r < 4; ++r) lp[(size_t)r * 4096] = acc[r];
    }
  }
}

// ---------- K5: softmax over t -> attn bf16 ----------
__global__ __launch_bounds__(256) void k_softmax2(const float* __restrict__ L,
                                                  unsigned* __restrict__ attnb) {
  __shared__ float red[8];
  size_t base = (size_t)blockIdx.x * 4096;
  int tid = threadIdx.x, wid = tid >> 6, lane = tid & 63;
  float4 v[4];
  float m = -3.4e38f;
#pragma unroll
  for (int k = 0; k < 4; ++k) {
    v[k] = *(const float4*)(L + base + tid * 16 + k * 4);
    m = fmaxf(m, fmaxf(fmaxf(v[k].x, v[k].y), fmaxf(v[k].z, v[k].w)));
  }
  m = wmax(m);
  if (lane == 0) red[wid] = m;
  __syncthreads();
  m = fmaxf(fmaxf(red[0], red[1]), fmaxf(red[2], red[3]));
  float ssum = 0.f;
#pragma unroll
  for (int k = 0; k < 4; ++k) {
    v[k].x = expf(v[k].x - m); v[k].y = expf(v[k].y - m);
    v[k].z = expf(v[k].z - m); v[k].w = expf(v[k].w - m);
    ssum += v[k].x + v[k].y + v[k].z + v[k].w;
  }
  ssum = wsum(ssum);
  if (lane == 0) red[4 + wid] = ssum;
  __syncthreads();
  ssum = red[4] + red[5] + red[6] + red[7];
  float inv = 1.f / (ssum * (1.f + 1e-8f));
  unsigned o[8];
#pragma unroll
  for (int k = 0; k < 4; ++k) {
    o[k * 2]     = (unsigned)f2bf(v[k].x * inv) | ((unsigned)f2bf(v[k].y * inv) << 16);
    o[k * 2 + 1] = (unsigned)f2bf(v[k].z * inv) | ((unsigned)f2bf(v[k].w * inv) << 16);
  }
  unsigned* dp = attnb + (size_t)blockIdx.x * 2048 + tid * 8;
  *(uint4*)dp       = *(uint4*)&o[0];
  *(uint4*)(dp + 4) = *(uint4*)&o[4];
}

// ---------- K6: AX via MFMA: AX[s][d] = sum_t attn[s][t] xT[d][t] ----------
__global__ __launch_bounds__(256) void k_ax_m(const unsigned* __restrict__ xT,
                                              const unsigned* __restrict__ attnb,
                                              float* __restrict__ axg) {
  __shared__ float red[4][16][16];
  int n = blockIdx.y, d0 = blockIdx.x * 16;
  int tid = threadIdx.x, wv = tid >> 6, l = tid & 63;
  int col = l & 15, g = l >> 4;
  const unsigned* ap = attnb + ((size_t)n * 8 + (col & 7)) * 2048 + wv * 512 + g * 4;
  const unsigned* bp = xT + ((size_t)n * 256 + d0 + col) * 2048 + wv * 512 + g * 4;
  f32x4 acc = {0.f, 0.f, 0.f, 0.f};
#pragma unroll 4
  for (int ks = 0; ks < 32; ++ks) {
    U4B aa, bb;
    aa.u = *(const uint4*)(ap + ks * 16);
    bb.u = *(const uint4*)(bp + ks * 16);
    acc = __builtin_amdgcn_mfma_f32_16x16x32_bf16(aa.b, bb.b, acc, 0, 0, 0);
  }
#pragma unroll
  for (int r = 0; r < 4; ++r) red[wv][g * 4 + r][col] = acc[r];
  __syncthreads();
  int row = tid >> 4, c2 = tid & 15;
  if (row < 8) {
    float ssum = red[0][row][c2] + red[1][row][c2] + red[2][row][c2] + red[3][row][c2];
    axg[((size_t)n * 8 + row) * 256 + d0 + c2] = ssum;
  }
}

// ---------- K7: update (4 slots/block): AX@WvT, GRU, LN, MLP ----------
__global__ __launch_bounds__(512) void k_update2(
    const float* __restrict__ axg, const float* __restrict__ slots_in,
    const float* __restrict__ WvT, const float* __restrict__ WihT,
    const float* __restrict__ WhhT, const float* __restrict__ b_ih,
    const float* __restrict__ b_hh, const float* __restrict__ W1T,
    const float* __restrict__ b1, const float* __restrict__ W2T,
    const float* __restrict__ b2, const float* __restrict__ g2,
    const float* __restrict__ bt2, float* __restrict__ slots_out) {
  __shared__ float ax[4][256];
  __shared__ float sp[4][256];
  __shared__ float upd[4][256];
  __shared__ float gi[4][768];
  __shared__ float gh[4][768];
  __shared__ float sn[4][256];
  __shared__ float lnv[4][256];
  __shared__ float hid[4][256];
  __shared__ float red[16];
  int n = blockIdx.x, sg = blockIdx.y * 4;
  int tid = threadIdx.x;
  for (int i = tid; i < 1024; i += 512) {
    int sl = i >> 8, d = i & 255;
    ax[sl][d] = axg[((size_t)n * 8 + sg + sl) * 256 + d];
    sp[sl][d] = slots_in[((size_t)n * 8 + sg + sl) * 256 + d];
  }
  __syncthreads();
  int e = tid & 255, h = tid >> 8;
  {
    float a0 = 0.f, a1 = 0.f;
    for (int d = 0; d < 256; ++d) {
      float w = WvT[d * 256 + e];
      a0 += ax[h * 2][d] * w;
      a1 += ax[h * 2 + 1][d] * w;
    }
    upd[h * 2][e] = a0;
    upd[h * 2 + 1][e] = a1;
  }
  __syncthreads();
  for (int jj = tid; jj < 1536; jj += 512) {
    bool ihs = jj < 768;
    int j = ihs ? jj : jj - 768;
    const float* WT = ihs ? WihT : WhhT;
    const float* src = ihs ? &upd[0][0] : &sp[0][0];
    float a0 = 0.f, a1 = 0.f, a2 = 0.f, a3 = 0.f;
    for (int d = 0; d < 256; ++d) {
      float w = WT[(size_t)d * 768 + j];
      a0 += src[d] * w;
      a1 += src[256 + d] * w;
      a2 += src[512 + d] * w;
      a3 += src[768 + d] * w;
    }
    float bb = ihs ? b_ih[j] : b_hh[j];
    float* dst = ihs ? &gi[0][0] : &gh[0][0];
    dst[j] = a0 + bb;
    dst[768 + j] = a1 + bb;
    dst[1536 + j] = a2 + bb;
    dst[2304 + j] = a3 + bb;
  }
  __syncthreads();
  for (int i = tid; i < 1024; i += 512) {
    int sl = i >> 8, j = i & 255;
    float r = sigmf(gi[sl][j] + gh[sl][j]);
    float z = sigmf(gi[sl][j + 256] + gh[sl][j + 256]);
    float hh = tanhf(gi[sl][j + 512] + r * gh[sl][j + 512]);
    sn[sl][j] = (1.f - z) * hh + z * sp[sl][j];
  }
  __syncthreads();
  {
    int sl = tid >> 7, qq = tid & 127;
    float v0 = sn[sl][qq], v1 = sn[sl][qq + 128];
    float ps = wsum(v0 + v1);
    float pq = wsum(v0 * v0 + v1 * v1);
    int wid = tid >> 6;
    if ((tid & 63) == 0) { red[wid] = ps; red[8 + wid] = pq; }
    __syncthreads();
    float ssum = red[sl * 2] + red[sl * 2 + 1];
    float sqq  = red[8 + sl * 2] + red[8 + sl * 2 + 1];
    float mu = ssum * (1.f / 256.f);
    float var = sqq * (1.f / 256.f) - mu * mu;
    float rs = rsqrtf(var + 1e-5f);
    lnv[sl][qq]       = (v0 - mu) * rs * g2[qq] + bt2[qq];
    lnv[sl][qq + 128] = (v1 - mu) * rs * g2[qq + 128] + bt2[qq + 128];
  }
  __syncthreads();
  {
    float a0 = 0.f, a1 = 0.f;
    for (int d = 0; d < 256; ++d) {
      float w = W1T[d * 256 + e];
      a0 += lnv[h * 2][d] * w;
      a1 += lnv[h * 2 + 1][d] * w;
    }
    hid[h * 2][e]     = fmaxf(a0 + b1[e], 0.f);
    hid[h * 2 + 1][e] = fmaxf(a1 + b1[e], 0.f);
  }
  __syncthreads();
  {
    float a0 = 0.f, a1 = 0.f;
    for (int d = 0; d < 256; ++d) {
      float w = W2T[d * 256 + e];
      a0 += hid[h * 2][d] * w;
      a1 += hid[h * 2 + 1][d] * w;
    }
    slots_out[((size_t)n * 8 + sg + h * 2) * 256 + e]     = sn[h * 2][e] + a0 + b2[e];
    slots_out[((size_t)n * 8 + sg + h * 2 + 1) * 256 + e] = sn[h * 2 + 1][e] + a1 + b2[e];
  }
}

extern "C" void kernel_launch(void* const* d_in, const int* in_sizes, int n_in,
                              void* d_out, int out_size, void* d_ws, size_t ws_size,
                              hipStream_t stream) {
  (void)in_sizes; (void)n_in; (void)out_size; (void)ws_size;
  const float* inputs = (const float*)d_in[0];
  const float* noise  = (const float*)d_in[1];
  const float* smu    = (const float*)d_in[2];
  const float* slsig  = (const float*)d_in[3];
  const float* Wq     = (const float*)d_in[4];
  const float* Wk     = (const float*)d_in[5];
  const float* Wv     = (const float*)d_in[6];
  const float* W_ih   = (const float*)d_in[7];
  const float* W_hh   = (const float*)d_in[8];
  const float* b_ih   = (const float*)d_in[9];
  const float* b_hh   = (const float*)d_in[10];
  const float* W1     = (const float*)d_in[11];
  const float* b1     = (const float*)d_in[12];
  const float* W2     = (const float*)d_in[13];
  const float* b2     = (const float*)d_in[14];
  const float* lin_g  = (const float*)d_in[15];
  const float* lin_b  = (const float*)d_in[16];
  const float* lsl_g  = (const float*)d_in[17];
  const float* lsl_b  = (const float*)d_in[18];
  const float* lml_g  = (const float*)d_in[19];
  const float* lml_b  = (const float*)d_in[20];
  float* out = (float*)d_out;
  char* ws = (char*)d_ws;
  unsigned* x    = (unsigned*)(ws + 0);           // 134217728
  unsigned* xT   = (unsigned*)(ws + 134217728);   // 134217728
  float* logits  = (float*)(ws + 268435456);      // 8388608
  unsigned* attnb= (unsigned*)(ws + 276824064);   // 4194304 + slack
  float* qw      = (float*)(ws + 281083904);      // 524288 + slack
  float* axg     = (float*)(ws + 281616384);      // 524288
  float* WqT     = (float*)(ws + 282140672);      // 262144
  float* WvT     = (float*)(ws + 282402816);      // 262144
  float* WihT    = (float*)(ws + 282664960);      // 786432
  float* WhhT    = (float*)(ws + 283451392);      // 786432
  float* W1T     = (float*)(ws + 284237824);      // 262144
  float* W2T     = (float*)(ws + 284499968);      // 262144

  k_tr<<<dim3(8, 8), 256, 0, stream>>>(Wq, WqT, 256, 256);
  k_tr<<<dim3(8, 8), 256, 0, stream>>>(Wv, WvT, 256, 256);
  k_tr<<<dim3(8, 24), 256, 0, stream>>>(W_ih, WihT, 768, 256);
  k_tr<<<dim3(8, 24), 256, 0, stream>>>(W_hh, WhhT, 768, 256);
  k_tr<<<dim3(8, 8), 256, 0, stream>>>(W1, W1T, 256, 256);
  k_tr<<<dim3(8, 8), 256, 0, stream>>>(W2, W2T, 256, 256);

  k_ln_in<<<dim3(BATCH * TOKENS / 4), 256, 0, stream>>>(inputs, lin_g, lin_b, x);
  k_trx<<<dim3(32, 2, BATCH), 256, 0, stream>>>(x, xT);
  k_init<<<dim3(512), 256, 0, stream>>>(smu, slsig, noise, out);
  for (int it = 0; it < 3; ++it) {
    k_qw2<<<dim3(BATCH, 2), 512, 0, stream>>>(out, lsl_g, lsl_b, WqT, Wk, qw);
    k_logits_m<<<dim3(16, BATCH), 256, 0, stream>>>(x, qw, logits);
    k_softmax2<<<dim3(512), 256, 0, stream>>>(logits, attnb);
    k_ax_m<<<dim3(16, BATCH), 256, 0, stream>>>(xT, attnb, axg);
    k_update2<<<dim3(BATCH, 2), 512, 0, stream>>>(axg, out, WvT, WihT, WhhT, b_ih,
                                                  b_hh, W1T, b1, W2T, b2, lml_g, lml_b, out);
  }
}

// Round 6
// 596.945 us; speedup vs baseline: 1.1259x; 1.1259x over previous
//
#include <hip/hip_runtime.h>
#include <math.h>

#define DIM 256
#define NSLOTS 8
#define TOKENS 4096
#define BATCH 64

typedef __attribute__((ext_vector_type(8))) short bf16x8;
typedef __attribute__((ext_vector_type(4))) float f32x4;

union U4B { uint4 u; bf16x8 b; };

// ---------- helpers ----------
__device__ __forceinline__ float wsum(float v) {
#pragma unroll
  for (int m = 32; m >= 1; m >>= 1) v += __shfl_xor(v, m);
  return v;
}
__device__ __forceinline__ unsigned short f2bf(float f) {
  unsigned u = __float_as_uint(f);
  u += 0x7fffu + ((u >> 16) & 1u);
  return (unsigned short)(u >> 16);
}
__device__ __forceinline__ float sigmf(float x) { return 1.f / (1.f + expf(-x)); }

// ---------- K0: 32x32 tiled fp32 transpose src[R][C] -> dst[C][R] ----------
__global__ __launch_bounds__(256) void k_tr(const float* __restrict__ src,
                                            float* __restrict__ dst, int R, int C) {
  __shared__ float t[32][33];
  int c0 = blockIdx.x * 32, r0 = blockIdx.y * 32;
  int ci = threadIdx.x & 31, r8 = threadIdx.x >> 5;
#pragma unroll
  for (int k = 0; k < 4; ++k) {
    int r = r8 + k * 8;
    t[r][ci] = src[(size_t)(r0 + r) * C + c0 + ci];
  }
  __syncthreads();
#pragma unroll
  for (int k = 0; k < 4; ++k) {
    int r = r8 + k * 8;
    dst[(size_t)(c0 + r) * R + r0 + ci] = t[ci][r];
  }
}

// ---------- K1: LN(inputs) -> x bf16 row-major (packed pairs), coalesced ----------
__global__ __launch_bounds__(256) void k_ln_in(const float* __restrict__ in,
                                               const float* __restrict__ g,
                                               const float* __restrict__ b,
                                               unsigned* __restrict__ x) {
  int row = blockIdx.x * 4 + (threadIdx.x >> 6);
  int lane = threadIdx.x & 63;
  const float* p = in + (size_t)row * DIM + lane * 4;
  float4 v = *(const float4*)p;
  float s  = wsum(v.x + v.y + v.z + v.w);
  float sq = wsum(v.x * v.x + v.y * v.y + v.z * v.z + v.w * v.w);
  float mu = s * (1.f / 256.f);
  float var = sq * (1.f / 256.f) - mu * mu;
  float rs = rsqrtf(var + 1e-5f);
  float4 gg = *(const float4*)(g + lane * 4);
  float4 bb = *(const float4*)(b + lane * 4);
  float y0 = (v.x - mu) * rs * gg.x + bb.x;
  float y1 = (v.y - mu) * rs * gg.y + bb.y;
  float y2 = (v.z - mu) * rs * gg.z + bb.z;
  float y3 = (v.w - mu) * rs * gg.w + bb.w;
  uint2 o;
  o.x = (unsigned)f2bf(y0) | ((unsigned)f2bf(y1) << 16);
  o.y = (unsigned)f2bf(y2) | ((unsigned)f2bf(y3) << 16);
  *(uint2*)(x + (size_t)row * 128 + lane * 2) = o;
}

// ---------- K1b: bf16 transpose x[n][t][d] -> xT[n][d][t], 128x128 tiles ----------
__global__ __launch_bounds__(256) void k_trx(const unsigned* __restrict__ x,
                                             unsigned* __restrict__ xT) {
  __shared__ unsigned u[128][65];
  int tt = blockIdx.x, dt = blockIdx.y, n = blockIdx.z;
  int tid = threadIdx.x;
  int t0 = tt * 128, c0 = dt * 64;
  {
    int row = tid >> 1, half = tid & 1;
    const unsigned* sp = x + ((size_t)n * 4096 + t0 + row) * 128 + c0 + half * 32;
    unsigned* dr = &u[row][half * 32];
#pragma unroll
    for (int j = 0; j < 8; ++j) {
      uint4 vv = *(const uint4*)(sp + j * 4);
      dr[j * 4 + 0] = vv.x;
      dr[j * 4 + 1] = vv.y;
      dr[j * 4 + 2] = vv.z;
      dr[j * 4 + 3] = vv.w;
    }
  }
  __syncthreads();
#pragma unroll
  for (int p = 0; p < 8; ++p) {
    int dl = p * 16 + (tid >> 4);
    int c = dl >> 1, hi = dl & 1;
    unsigned o[4];
#pragma unroll
    for (int k = 0; k < 4; ++k) {
      int j = (tid & 15) * 4 + k;
      unsigned u0 = u[2 * j][c], u1 = u[2 * j + 1][c];
      unsigned h0 = hi ? (u0 >> 16) : (u0 & 0xffffu);
      unsigned h1 = hi ? (u1 >> 16) : (u1 & 0xffffu);
      o[k] = h0 | (h1 << 16);
    }
    unsigned* dp = xT + ((size_t)n * 256 + dt * 128 + dl) * 2048 + tt * 64 + (tid & 15) * 4;
    *(uint4*)dp = *(uint4*)&o[0];
  }
}

// ---------- K2: slots = mu + exp(logsigma)*noise ----------
__global__ __launch_bounds__(256) void k_init(const float* __restrict__ mu,
                                              const float* __restrict__ ls,
                                              const float* __restrict__ noise,
                                              float* __restrict__ slots) {
  int i = blockIdx.x * 256 + threadIdx.x;
  int sd = i & 2047;
  slots[i] = mu[sd] + expf(ls[sd]) * noise[i];
}

// ---------- K3: qwb[n][s] = bf16( LN(slots[n,s]) @ WqT @ Wk * scale ) ----------
// grid (64, 8): one block per (n, slot), 256 threads
__global__ __launch_bounds__(256) void k_qw3(const float* __restrict__ slots,
                                             const float* __restrict__ g,
                                             const float* __restrict__ b,
                                             const float* __restrict__ WqT,
                                             const float* __restrict__ Wk,
                                             unsigned* __restrict__ qwb) {
  __shared__ float ln[256];
  __shared__ float q[256];
  __shared__ float red[8];
  int n = blockIdx.x, s = blockIdx.y, tid = threadIdx.x;
  float v = slots[((size_t)n * 8 + s) * 256 + tid];
  float ps = wsum(v), pq = wsum(v * v);
  if ((tid & 63) == 0) { red[tid >> 6] = ps; red[4 + (tid >> 6)] = pq; }
  __syncthreads();
  float sum = red[0] + red[1] + red[2] + red[3];
  float sqq = red[4] + red[5] + red[6] + red[7];
  float mu = sum * (1.f / 256.f);
  float var = sqq * (1.f / 256.f) - mu * mu;
  float rs = rsqrtf(var + 1e-5f);
  ln[tid] = (v - mu) * rs * g[tid] + b[tid];
  __syncthreads();
  float a = 0.f;
  for (int d = 0; d < 256; ++d) a += ln[d] * WqT[d * 256 + tid];
  q[tid] = a;
  __syncthreads();
  float c = 0.f;
  for (int e = 0; e < 256; ++e) c += q[e] * Wk[e * 256 + tid];
  c *= 0.0625f;
  __syncthreads();          // ln no longer needed
  ln[tid] = c;
  __syncthreads();
  if (tid < 128) {
    unsigned w = (unsigned)f2bf(ln[2 * tid]) | ((unsigned)f2bf(ln[2 * tid + 1]) << 16);
    qwb[((size_t)n * 8 + s) * 128 + tid] = w;
  }
}

// ---------- K4: logits (MFMA) + per-chunk softmax partials ----------
// grid (8 chunks of 512 tokens, 64 n), 256 thr = 4 waves (128 tokens each)
__global__ __launch_bounds__(256) void k_logsm(const unsigned* __restrict__ x,
                                               const unsigned* __restrict__ qwb,
                                               float* __restrict__ logits,
                                               float2* __restrict__ stats) {
  __shared__ float ls[8][520];
  int ch = blockIdx.x, n = blockIdx.y;
  int tid = threadIdx.x, wv = tid >> 6, l = tid & 63;
  int col = l & 15, g = l >> 4;
  uint4 a[8];
  {
    const unsigned* ap = qwb + ((size_t)n * 8 + (l & 7)) * 128 + g * 4;
#pragma unroll
    for (int kk = 0; kk < 8; ++kk) a[kk] = *(const uint4*)(ap + kk * 16);
  }
  int tb = ch * 512 + wv * 128;
#pragma unroll
  for (int tt = 0; tt < 8; ++tt) {
    int t0 = tb + tt * 16;
    const unsigned* bp = x + ((size_t)n * 4096 + t0 + col) * 128 + g * 4;
    f32x4 acc = {0.f, 0.f, 0.f, 0.f};
#pragma unroll
    for (int kk = 0; kk < 8; ++kk) {
      U4B aa, bb;
      aa.u = a[kk];
      bb.u = *(const uint4*)(bp + kk * 16);
      acc = __builtin_amdgcn_mfma_f32_16x16x32_bf16(aa.b, bb.b, acc, 0, 0, 0);
    }
    if (g < 2) {
#pragma unroll
      for (int r = 0; r < 4; ++r) ls[g * 4 + r][wv * 128 + tt * 16 + col] = acc[r];
    }
  }
  __syncthreads();
  int s = tid >> 5, q = tid & 31;
  float vv[16];
  float M = -3.4e38f;
#pragma unroll
  for (int j = 0; j < 16; ++j) {
    vv[j] = ls[s][q + j * 32];
    M = fmaxf(M, vv[j]);
  }
#pragma unroll
  for (int m = 16; m >= 1; m >>= 1) M = fmaxf(M, __shfl_xor(M, m));
  float S = 0.f;
#pragma unroll
  for (int j = 0; j < 16; ++j) S += expf(vv[j] - M);
#pragma unroll
  for (int m = 16; m >= 1; m >>= 1) S += __shfl_xor(S, m);
  if (q == 0) stats[((size_t)n * 8 + s) * 8 + ch] = make_float2(M, S);
  float* lp = logits + ((size_t)n * 8 + s) * 4096 + ch * 512;
#pragma unroll
  for (int j = 0; j < 16; ++j) lp[q + j * 32] = vv[j];
}

// ---------- K5: attn (from logits+stats) + AX partial (MFMA) ----------
// grid (8 chunks, 64 n), 256 thr = 4 waves (4 d-tiles of 16 each)
__global__ __launch_bounds__(256) void k_attnax(const unsigned* __restrict__ xT,
                                                const float* __restrict__ logits,
                                                const float2* __restrict__ stats,
                                                float* __restrict__ axp) {
  __shared__ unsigned at2[8][256];
  __shared__ float MS[8][2];
  int ch = blockIdx.x, n = blockIdx.y;
  int tid = threadIdx.x;
  if (tid < 8) {
    const float2* st = stats + ((size_t)n * 8 + tid) * 8;
    float M = -3.4e38f;
#pragma unroll
    for (int c = 0; c < 8; ++c) M = fmaxf(M, st[c].x);
    float S = 0.f;
#pragma unroll
    for (int c = 0; c < 8; ++c) S += st[c].y * expf(st[c].x - M);
    MS[tid][0] = M;
    MS[tid][1] = 1.f / (S * (1.f + 1e-8f));
  }
  __syncthreads();
  {
    int s = tid >> 5, q = tid & 31;
    float M = MS[s][0], inv = MS[s][1];
    const float* lp = logits + ((size_t)n * 8 + s) * 4096 + ch * 512;
#pragma unroll
    for (int j = 0; j < 8; ++j) {
      int w = q + j * 32;
      float2 e = *(const float2*)(lp + 2 * w);
      float e0 = expf(e.x - M) * inv;
      float e1 = expf(e.y - M) * inv;
      at2[s][w] = (unsigned)f2bf(e0) | ((unsigned)f2bf(e1) << 16);
    }
  }
  __syncthreads();
  int wv = tid >> 6, l = tid & 63;
  int col = l & 15, g = l >> 4;
  const unsigned* apl = &at2[l & 7][0];
#pragma unroll
  for (int dt = 0; dt < 4; ++dt) {
    int d0 = (wv * 4 + dt) * 16;
    const unsigned* bp = xT + ((size_t)n * 256 + d0 + col) * 2048 + ch * 256 + g * 4;
    f32x4 acc = {0.f, 0.f, 0.f, 0.f};
#pragma unroll
    for (int kk = 0; kk < 8; ++kk) {
      U4B aa, bb;
      aa.u = *(const uint4*)(apl + kk * 16 + g * 4);
      bb.u = *(const uint4*)(bp + kk * 16);
      acc = __builtin_amdgcn_mfma_f32_16x16x32_bf16(aa.b, bb.b, acc, 0, 0, 0);
    }
    if (g < 2) {
#pragma unroll
      for (int r = 0; r < 4; ++r)
        axp[(((size_t)n * 8 + ch) * 8 + g * 4 + r) * 256 + d0 + col] = acc[r];
    }
  }
}

// ---------- K7: update (4 slots/block): reduce partials, Wv, GRU, LN, MLP ----------
__global__ __launch_bounds__(512) void k_update2(
    const float* __restrict__ axp, const float* __restrict__ slots_in,
    const float* __restrict__ WvT, const float* __restrict__ WihT,
    const float* __restrict__ WhhT, const float* __restrict__ b_ih,
    const float* __restrict__ b_hh, const float* __restrict__ W1T,
    const float* __restrict__ b1, const float* __restrict__ W2T,
    const float* __restrict__ b2, const float* __restrict__ g2,
    const float* __restrict__ bt2, float* __restrict__ slots_out) {
  __shared__ float ax[4][256];
  __shared__ float sp[4][256];
  __shared__ float upd[4][256];
  __shared__ float gi[4][768];
  __shared__ float gh[4][768];
  __shared__ float sn[4][256];
  __shared__ float lnv[4][256];
  __shared__ float hid[4][256];
  __shared__ float red[16];
  int n = blockIdx.x, sg = blockIdx.y * 4;
  int tid = threadIdx.x;
  for (int i = tid; i < 1024; i += 512) {
    int sl = i >> 8, d = i & 255;
    const float* pp = axp + ((size_t)n * 64 + sg + sl) * 256 + d;
    float a = 0.f;
#pragma unroll
    for (int c = 0; c < 8; ++c) a += pp[(size_t)c * 2048];
    ax[sl][d] = a;
    sp[sl][d] = slots_in[((size_t)n * 8 + sg + sl) * 256 + d];
  }
  __syncthreads();
  int e = tid & 255, h = tid >> 8;
  {
    float a0 = 0.f, a1 = 0.f;
    for (int d = 0; d < 256; ++d) {
      float w = WvT[d * 256 + e];
      a0 += ax[h * 2][d] * w;
      a1 += ax[h * 2 + 1][d] * w;
    }
    upd[h * 2][e] = a0;
    upd[h * 2 + 1][e] = a1;
  }
  __syncthreads();
  for (int jj = tid; jj < 1536; jj += 512) {
    bool ihs = jj < 768;
    int j = ihs ? jj : jj - 768;
    const float* WT = ihs ? WihT : WhhT;
    const float* src = ihs ? &upd[0][0] : &sp[0][0];
    float a0 = 0.f, a1 = 0.f, a2 = 0.f, a3 = 0.f;
    for (int d = 0; d < 256; ++d) {
      float w = WT[(size_t)d * 768 + j];
      a0 += src[d] * w;
      a1 += src[256 + d] * w;
      a2 += src[512 + d] * w;
      a3 += src[768 + d] * w;
    }
    float bb = ihs ? b_ih[j] : b_hh[j];
    float* dst = ihs ? &gi[0][0] : &gh[0][0];
    dst[j] = a0 + bb;
    dst[768 + j] = a1 + bb;
    dst[1536 + j] = a2 + bb;
    dst[2304 + j] = a3 + bb;
  }
  __syncthreads();
  for (int i = tid; i < 1024; i += 512) {
    int sl = i >> 8, j = i & 255;
    float r = sigmf(gi[sl][j] + gh[sl][j]);
    float z = sigmf(gi[sl][j + 256] + gh[sl][j + 256]);
    float hh = tanhf(gi[sl][j + 512] + r * gh[sl][j + 512]);
    sn[sl][j] = (1.f - z) * hh + z * sp[sl][j];
  }
  __syncthreads();
  {
    int sl = tid >> 7, qq = tid & 127;
    float v0 = sn[sl][qq], v1 = sn[sl][qq + 128];
    float ps = wsum(v0 + v1);
    float pq = wsum(v0 * v0 + v1 * v1);
    int wid = tid >> 6;
    if ((tid & 63) == 0) { red[wid] = ps; red[8 + wid] = pq; }
    __syncthreads();
    float ssum = red[sl * 2] + red[sl * 2 + 1];
    float sqq  = red[8 + sl * 2] + red[8 + sl * 2 + 1];
    float mu = ssum * (1.f / 256.f);
    float var = sqq * (1.f / 256.f) - mu * mu;
    float rs = rsqrtf(var + 1e-5f);
    lnv[sl][qq]       = (v0 - mu) * rs * g2[qq] + bt2[qq];
    lnv[sl][qq + 128] = (v1 - mu) * rs * g2[qq + 128] + bt2[qq + 128];
  }
  __syncthreads();
  {
    float a0 = 0.f, a1 = 0.f;
    for (int d = 0; d < 256; ++d) {
      float w = W1T[d * 256 + e];
      a0 += lnv[h * 2][d] * w;
      a1 += lnv[h * 2 + 1][d] * w;
    }
    hid[h * 2][e]     = fmaxf(a0 + b1[e], 0.f);
    hid[h * 2 + 1][e] = fmaxf(a1 + b1[e], 0.f);
  }
  __syncthreads();
  {
    float a0 = 0.f, a1 = 0.f;
    for (int d = 0; d < 256; ++d) {
      float w = W2T[d * 256 + e];
      a0 += hid[h * 2][d] * w;
      a1 += hid[h * 2 + 1][d] * w;
    }
    slots_out[((size_t)n * 8 + sg + h * 2) * 256 + e]     = sn[h * 2][e] + a0 + b2[e];
    slots_out[((size_t)n * 8 + sg + h * 2 + 1) * 256 + e] = sn[h * 2 + 1][e] + a1 + b2[e];
  }
}

extern "C" void kernel_launch(void* const* d_in, const int* in_sizes, int n_in,
                              void* d_out, int out_size, void* d_ws, size_t ws_size,
                              hipStream_t stream) {
  (void)in_sizes; (void)n_in; (void)out_size; (void)ws_size;
  const float* inputs = (const float*)d_in[0];
  const float* noise  = (const float*)d_in[1];
  const float* smu    = (const float*)d_in[2];
  const float* slsig  = (const float*)d_in[3];
  const float* Wq     = (const float*)d_in[4];
  const float* Wk     = (const float*)d_in[5];
  const float* Wv     = (const float*)d_in[6];
  const float* W_ih   = (const float*)d_in[7];
  const float* W_hh   = (const float*)d_in[8];
  const float* b_ih   = (const float*)d_in[9];
  const float* b_hh   = (const float*)d_in[10];
  const float* W1     = (const float*)d_in[11];
  const float* b1     = (const float*)d_in[12];
  const float* W2     = (const float*)d_in[13];
  const float* b2     = (const float*)d_in[14];
  const float* lin_g  = (const float*)d_in[15];
  const float* lin_b  = (const float*)d_in[16];
  const float* lsl_g  = (const float*)d_in[17];
  const float* lsl_b  = (const float*)d_in[18];
  const float* lml_g  = (const float*)d_in[19];
  const float* lml_b  = (const float*)d_in[20];
  float* out = (float*)d_out;
  char* ws = (char*)d_ws;
  unsigned* x    = (unsigned*)(ws + 0);           // 134217728
  unsigned* xT   = (unsigned*)(ws + 134217728);   // 134217728
  float* logits  = (float*)(ws + 268435456);      // 8388608
  unsigned* qwb  = (unsigned*)(ws + 276824064);   // 262144
  float2* stats  = (float2*)(ws + 277086208);     // 32768
  float* axp     = (float*)(ws + 277118976);      // 4194304
  float* WqT     = (float*)(ws + 281313280);      // 262144
  float* WvT     = (float*)(ws + 281575424);      // 262144
  float* WihT    = (float*)(ws + 281837568);      // 786432
  float* WhhT    = (float*)(ws + 282624000);      // 786432
  float* W1T     = (float*)(ws + 283410432);      // 262144
  float* W2T     = (float*)(ws + 283672576);      // 262144

  k_tr<<<dim3(8, 8), 256, 0, stream>>>(Wq, WqT, 256, 256);
  k_tr<<<dim3(8, 8), 256, 0, stream>>>(Wv, WvT, 256, 256);
  k_tr<<<dim3(8, 24), 256, 0, stream>>>(W_ih, WihT, 768, 256);
  k_tr<<<dim3(8, 24), 256, 0, stream>>>(W_hh, WhhT, 768, 256);
  k_tr<<<dim3(8, 8), 256, 0, stream>>>(W1, W1T, 256, 256);
  k_tr<<<dim3(8, 8), 256, 0, stream>>>(W2, W2T, 256, 256);

  k_ln_in<<<dim3(BATCH * TOKENS / 4), 256, 0, stream>>>(inputs, lin_g, lin_b, x);
  k_trx<<<dim3(32, 2, BATCH), 256, 0, stream>>>(x, xT);
  k_init<<<dim3(512), 256, 0, stream>>>(smu, slsig, noise, out);
  for (int it = 0; it < 3; ++it) {
    k_qw3<<<dim3(BATCH, 8), 256, 0, stream>>>(out, lsl_g, lsl_b, WqT, Wk, qwb);
    k_logsm<<<dim3(8, BATCH), 256, 0, stream>>>(x, qwb, logits, stats);
    k_attnax<<<dim3(8, BATCH), 256, 0, stream>>>(xT, logits, stats, axp);
    k_update2<<<dim3(BATCH, 2), 512, 0, stream>>>(axp, out, WvT, WihT, WhhT, b_ih,
                                                  b_hh, W1T, b1, W2T, b2, lml_g, lml_b, out);
  }
}